// Round 2
// 622.035 us; speedup vs baseline: 1.1224x; 1.1224x over previous
//
#include <hip/hip_runtime.h>

// MFMA-based fully-fused 5-layer bidirectional GRU.
//
// Block = 128 threads = 2 waves: wave0 = forward dir, wave1 = backward dir,
// 32 batch elements per block. Per step, ONE v_mfma_f32_32x32x16_f16 computes
// every gate pre-activation for all 32 batch elems of one direction:
//   A (32x16, f16, per-layer constant): row = 4*u + g, g in {r, z, i_n, h_n};
//     k0..9 = W_ih over the 10 input channels (ch = 2*unit + dir of prev layer),
//     k10..14 = W_hh over own-dir h, k15 = 0.  i_n and h_n kept in separate
//     rows so n = tanh(i_n + r*h_n) stays exact.  exp2 scale factors folded in.
//   B (16x32, f16, per step): col = batch; k0..9 = prev-layer output (LDS),
//     k10..14 = own h (register recurrence, repacked via 2 ds_bpermute + 2 v_perm).
//   C = bias fragment (re-added fresh every step for free).
// D layout (row=(reg&3)+8*(reg>>2)+4*half): each lane's register quad q holds all
// 4 gates of unit u = 2q+half -> activations are lane-local, h never leaves the wave.
//
// Inter-layer sequences: LDS f16 pair-planes seq[t][unit][batch], fwd in low
// half-word / bwd in high -> conflict-free b32 column reads, scalar b16 writes.
// Waves sync only at layer boundaries. Layer-4 bwd needs only ys[T-1] = its
// first step -> 1 step. LDS: 2*19200 (seq ping-pong) + 1920 (x f16) = 40320 B
// -> 4 blocks/CU = 8 waves/CU.

#define NB 262144
#define T 30

typedef _Float16 f16x8 __attribute__((ext_vector_type(8)));
typedef float f32x16 __attribute__((ext_vector_type(16)));

#define SIG_SCALE  (-1.4426950408889634f)   // -log2(e)
#define TANH_SCALE ( 2.8853900817779268f)   // 2*log2(e)

__device__ __forceinline__ float sig_s(float xs) {
    // x pre-scaled by -log2e: sigmoid(orig) = 1/(1+2^x)
    return __builtin_amdgcn_rcpf(1.0f + __builtin_amdgcn_exp2f(xs));
}
__device__ __forceinline__ float tanh_s(float xs) {
    // x pre-scaled by 2*log2e: tanh(orig) = 1 - 2/(1+2^x)
    return fmaf(-2.0f, __builtin_amdgcn_rcpf(1.0f + __builtin_amdgcn_exp2f(xs)), 1.0f);
}
__device__ __forceinline__ unsigned packh(_Float16 a, _Float16 b) {
    union { _Float16 f; unsigned short s; } ua, ub;
    ua.f = a; ub.f = b;
    return (unsigned)ua.s | ((unsigned)ub.s << 16);
}

// One direction of one layer. seqR/seqW are [T][5][32] u32 pair-planes.
template <bool IS_L0, int NT, bool WRITE, bool STORE>
__device__ __forceinline__ void run_layer(
    const float* __restrict__ wih, const float* __restrict__ whh,
    const float* __restrict__ bih, const float* __restrict__ bhh,
    const unsigned* seqR, unsigned* seqW, const _Float16* xsp,
    float* outp, const int d, const int lane)
{
    const int lr   = lane & 31;    // A row (weights) / B,D column (batch)
    const int half = lane >> 5;    // k-half for A/B; unit parity for D quads
    const int u_r  = lr >> 2;
    const int g    = lr & 3;       // 0=r 1=z 2=i_n 3=h_n
    const bool rv  = lr < 20;

    // ---- A fragment: elem e <-> k = 8*half + e (same rule as B -> robust) ----
    f16x8 af;
#pragma unroll
    for (int e = 0; e < 8; e++) {
        const int k = 8 * half + e;
        float v = 0.f;
        if (rv) {
            if (!IS_L0) {
                if (k < 10) {                       // input channels, ch = 2*uk + dk
                    const int j = (k & 1) * 5 + (k >> 1);   // prev-layer concat col
                    if (g == 0)      v = SIG_SCALE  * wih[u_r * 10 + j];
                    else if (g == 1) v = SIG_SCALE  * wih[(5 + u_r) * 10 + j];
                    else if (g == 2) v = TANH_SCALE * wih[(10 + u_r) * 10 + j];
                } else if (k < 15) {                // own-dir hidden
                    const int uh = k - 10;
                    if (g == 0)      v = SIG_SCALE  * whh[u_r * 5 + uh];
                    else if (g == 1) v = SIG_SCALE  * whh[(5 + u_r) * 5 + uh];
                    else if (g == 3) v = TANH_SCALE * whh[(10 + u_r) * 5 + uh];
                }
            } else {
                if (k == 0) {                       // input dim 1
                    if (g == 0)      v = SIG_SCALE  * wih[u_r];
                    else if (g == 1) v = SIG_SCALE  * wih[5 + u_r];
                    else if (g == 2) v = TANH_SCALE * wih[10 + u_r];
                } else if (k >= 10 && k < 15) {
                    const int uh = k - 10;
                    if (g == 0)      v = SIG_SCALE  * whh[u_r * 5 + uh];
                    else if (g == 1) v = SIG_SCALE  * whh[(5 + u_r) * 5 + uh];
                    else if (g == 3) v = TANH_SCALE * whh[(10 + u_r) * 5 + uh];
                }
            }
        }
        af[e] = (_Float16)v;
    }

    // ---- bias fragment (C): quad q -> unit u = 2q+half, gates (r,z,i_n,h_n) ----
    f32x16 bc;
#pragma unroll
    for (int q = 0; q < 4; q++) {
        const int u = 2 * q + half;
        float b0 = 0.f, b1 = 0.f, b2 = 0.f, b3 = 0.f;
        if (q < 3 && u < 5) {
            b0 = SIG_SCALE  * (bih[u] + bhh[u]);
            b1 = SIG_SCALE  * (bih[5 + u] + bhh[5 + u]);
            b2 = TANH_SCALE * bih[10 + u];
            b3 = TANH_SCALE * bhh[10 + u];
        }
        bc[4 * q + 0] = b0; bc[4 * q + 1] = b1;
        bc[4 * q + 2] = b2; bc[4 * q + 3] = b3;
    }

    // ---- step loop ----
    const int sdir = d ? -1 : 1;
    const int p0   = d ? (T - 1) : 0;
    const unsigned* rbase = seqR + p0 * 160 + lr;            // planes at +0/+32/+64/+96/+128
    const int r0off = half ? 128 : 0;                        // half1 reads plane4 (ch8,9)
    const _Float16* xp = xsp + p0 * 32 + lr;
    _Float16* wbase = (_Float16*)seqW + p0 * 320 + lr * 2 + d;  // [pos][u][col][d]
    const int rstep = sdir * 160, wstep = sdir * 320, xstep = sdir * 32;
    const int paddr = (lane ^ 32) << 2;                      // cross-half partner

    float h0 = 0.f, h1 = 0.f, h2 = 0.f;
    unsigned pb1 = 0, pb2 = 0, pb3 = 0;                      // h-slots of B (k10..15)

#pragma unroll 2
    for (int s = 0; s < NT; s++) {
        // B operand: half0 = x channels 0..7; half1 = [x8,x9][h0,h1][h2,h3][h4,0]
        union { f16x8 v; unsigned u[4]; } B;
        if constexpr (!IS_L0) {
            B.u[0] = rbase[r0off];
            B.u[1] = half ? pb1 : rbase[32];
            B.u[2] = half ? pb2 : rbase[64];
            B.u[3] = half ? pb3 : rbase[96];
        } else {
            const unsigned xv = (unsigned)*(const unsigned short*)xp;  // zext f16 -> k1 slot = 0
            B.u[0] = half ? 0u : xv;
            B.u[1] = half ? pb1 : 0u;
            B.u[2] = half ? pb2 : 0u;
            B.u[3] = half ? pb3 : 0u;
        }

        const f32x16 D = __builtin_amdgcn_mfma_f32_32x32x16_f16(af, B.v, bc, 0, 0, 0);

        // activations: quad q = unit 2q+half; D[4q+..] = (r, z, i_n, h_n) pre-acts
        float r, z, n;
        r = sig_s(D[0]); z = sig_s(D[1]);
        n = tanh_s(fmaf(r, D[3], D[2]));
        h0 = fmaf(z, h0 - n, n);
        r = sig_s(D[4]); z = sig_s(D[5]);
        n = tanh_s(fmaf(r, D[7], D[6]));
        h1 = fmaf(z, h1 - n, n);
        if (half == 0) {                 // unit 4 lives only in half0 lanes
            r = sig_s(D[8]); z = sig_s(D[9]);
            n = tanh_s(fmaf(r, D[11], D[10]));
            h2 = fmaf(z, h2 - n, n);
        }

        // repack h (f16, RTN) for next step's B h-slots + seq write
        const _Float16 q0 = (_Float16)h0, q1 = (_Float16)h1, q2 = (_Float16)h2;
        const unsigned pk0 = packh(q0, q1);                  // [u(half), u(2+half)]
        const unsigned pk1 = packh(q2, (_Float16)0.f);       // [u4, 0] (half0); 0 (half1)
        const unsigned o0 = (unsigned)__builtin_amdgcn_ds_bpermute(paddr, (int)pk0);
        const unsigned o1 = (unsigned)__builtin_amdgcn_ds_bpermute(paddr, (int)pk1);
        pb1 = __builtin_amdgcn_perm(pk0, o0, 0x05040100u);   // [h_u0, h_u1]
        pb2 = __builtin_amdgcn_perm(pk0, o0, 0x07060302u);   // [h_u2, h_u3]
        pb3 = o1;                                            // [h_u4, 0]

        if constexpr (WRITE) {
            wbase[half * 64]       = q0;                     // plane u=half
            wbase[(2 + half) * 64] = q1;                     // plane u=2+half
            if (half == 0) wbase[4 * 64] = q2;               // plane u=4
            wbase += wstep;
        }
        rbase += rstep;
        if constexpr (IS_L0) xp += xstep;
    }

    if constexpr (STORE) {               // ys[T-1] for this direction
        outp[half]     = h0;
        outp[2 + half] = h1;
        if (half == 0) outp[4] = h2;
    }
}

__global__ void __launch_bounds__(128, 2) gru_all(
    const float* __restrict__ x,
    const float* __restrict__ wih0, const float* __restrict__ whh0,
    const float* __restrict__ bih0, const float* __restrict__ bhh0,
    const float* __restrict__ wihL, const float* __restrict__ whhL,
    const float* __restrict__ bihL, const float* __restrict__ bhhL,
    float* __restrict__ out)
{
    __shared__ unsigned seqA[T][5][32];      // 19200 B
    __shared__ unsigned seqB[T][5][32];      // 19200 B
    __shared__ _Float16 xs[T][32];           // 1920 B

    const int tid  = threadIdx.x;
    const int d    = tid >> 6;               // wave0 = fwd, wave1 = bwd
    const int lane = tid & 63;
    const int lr   = lane & 31;
    const long base = (long)blockIdx.x * 32;

    // stage x (coalesced, f32 -> f16)
    for (int f = tid; f < 32 * T; f += 128) {
        const int bb = f / T, tt = f - bb * T;
        xs[tt][bb] = (_Float16)x[(base + bb) * T + tt];
    }
    __syncthreads();

    run_layer<true, T, true, false>(wih0 + d * 15, whh0 + d * 75,
                                    bih0 + d * 15, bhh0 + d * 15,
                                    &seqB[0][0][0], &seqA[0][0][0], &xs[0][0],
                                    nullptr, d, lane);
    __syncthreads();

    {   // layer 1: seqA -> seqB
        const int od = d;
        run_layer<false, T, true, false>(wihL + od * 150, whhL + od * 75,
                                         bihL + od * 15, bhhL + od * 15,
                                         &seqA[0][0][0], &seqB[0][0][0], &xs[0][0],
                                         nullptr, d, lane);
    }
    __syncthreads();
    {   // layer 2: seqB -> seqA
        const int od = 2 + d;
        run_layer<false, T, true, false>(wihL + od * 150, whhL + od * 75,
                                         bihL + od * 15, bhhL + od * 15,
                                         &seqB[0][0][0], &seqA[0][0][0], &xs[0][0],
                                         nullptr, d, lane);
    }
    __syncthreads();
    {   // layer 3: seqA -> seqB
        const int od = 4 + d;
        run_layer<false, T, true, false>(wihL + od * 150, whhL + od * 75,
                                         bihL + od * 15, bhhL + od * 15,
                                         &seqA[0][0][0], &seqB[0][0][0], &xs[0][0],
                                         nullptr, d, lane);
    }
    __syncthreads();
    {   // layer 4: no seq write; fwd stores after 30 steps, bwd after 1 step
        const int od = 6 + d;
        float* op = out + (base + lr) * 10 + d * 5;
        if (d == 0)
            run_layer<false, T, false, true>(wihL + od * 150, whhL + od * 75,
                                             bihL + od * 15, bhhL + od * 15,
                                             &seqB[0][0][0], &seqA[0][0][0], &xs[0][0],
                                             op, d, lane);
        else
            run_layer<false, 1, false, true>(wihL + od * 150, whhL + od * 75,
                                             bihL + od * 15, bhhL + od * 15,
                                             &seqB[0][0][0], &seqA[0][0][0], &xs[0][0],
                                             op, d, lane);
    }
}

extern "C" void kernel_launch(void* const* d_in, const int* in_sizes, int n_in,
                              void* d_out, int out_size, void* d_ws, size_t ws_size,
                              hipStream_t stream) {
    const float* x    = (const float*)d_in[0];
    const float* wih0 = (const float*)d_in[1];
    const float* whh0 = (const float*)d_in[2];
    const float* bih0 = (const float*)d_in[3];
    const float* bhh0 = (const float*)d_in[4];
    const float* wihL = (const float*)d_in[5];
    const float* whhL = (const float*)d_in[6];
    const float* bihL = (const float*)d_in[7];
    const float* bhhL = (const float*)d_in[8];
    float* out = (float*)d_out;

    const int blocks = NB / 32;   // 32 batch elements per 128-thread block
    gru_all<<<blocks, 128, 0, stream>>>(x, wih0, whh0, bih0, bhh0,
                                        wihL, whhL, bihL, bhhL, out);
}

// Round 6
// 543.889 us; speedup vs baseline: 1.2837x; 1.1437x over previous
//
#include <hip/hip_runtime.h>

// MFMA-based fully-fused 5-layer bidirectional GRU.
//
// Block = 128 threads = 2 waves: wave0 = fwd, wave1 = bwd, 32 batch elements
// per block. Per step, ONE v_mfma_f32_32x32x16_f16 computes every gate
// pre-activation for all 32 batch elems of one direction:
//   A (32x16, f16, per-layer constant): row r = 8q+4h+g holds unit u=2q+1-h,
//     gate g in {r, z, i_n, h_n} (rows 16-19 & 24-31 zero). k0..9 = W_ih over
//     the 10 input channels, k10..14 = W_hh over own-dir h. i_n / h_n in
//     separate rows so n = tanh(i_n + r*h_n) stays exact. exp2 scales folded.
//   B (16x32, f16, per step): col = batch; k0..9 = prev-layer output (LDS,
//     prefetched one step ahead), k10..14 = own h (register recurrence).
//   C = bias fragment (re-added free every step).
// D layout (row=(reg&3)+8*(reg>>2)+4*half): lane quad q = unit u = 2q+1-half.
// With this mapping half1 lanes (which supply B's h-slots k10..14) own units
// {0,2,4} and need only {1,3} from half0 -> cross-half exchange is ONE
// ds_bpermute (hardware-verified primitive) + 2 v_perm, latency hidden under
// the independent unit-4 activation chain. (v_permlane32_swap_b32 attempts in
// r3/r4 failed numerically -> reverted to the verified bpermute.)
//
// Inter-layer sequences: LDS f16 pair-planes seq[t][unit][batch], fwd lo /
// bwd hi halfword -> conflict-free b32 column reads, b16 writes. Waves sync
// only at layer boundaries. Layer-4 bwd needs only ys[T-1] = its first step.
// LDS: 2*19200 + 1920 = 40320 B -> 4 blocks/CU = 8 waves/CU.

#define NB 262144
#define T 30

typedef _Float16 f16x8 __attribute__((ext_vector_type(8)));
typedef float f32x16 __attribute__((ext_vector_type(16)));

#define SIG_SCALE  (-1.4426950408889634f)   // -log2(e)
#define TANH_SCALE ( 2.8853900817779268f)   // 2*log2(e)

__device__ __forceinline__ float sig_s(float xs) {
    // x pre-scaled by -log2e: sigmoid(orig) = 1/(1+2^x)
    return __builtin_amdgcn_rcpf(1.0f + __builtin_amdgcn_exp2f(xs));
}
__device__ __forceinline__ float tanh_s(float xs) {
    // x pre-scaled by 2*log2e: tanh(orig) = 1 - 2/(1+2^x)
    return fmaf(-2.0f, __builtin_amdgcn_rcpf(1.0f + __builtin_amdgcn_exp2f(xs)), 1.0f);
}
__device__ __forceinline__ unsigned packh(_Float16 a, _Float16 b) {
    union { _Float16 f; unsigned short s; } ua, ub;
    ua.f = a; ub.f = b;
    return (unsigned)ua.s | ((unsigned)ub.s << 16);
}

// One direction of one layer. seqR/seqW are [T][5][32] u32 pair-planes.
template <bool IS_L0, int NT, bool WRITE, bool STORE>
__device__ __forceinline__ void run_layer(
    const float* __restrict__ wih, const float* __restrict__ whh,
    const float* __restrict__ bih, const float* __restrict__ bhh,
    const unsigned* seqR, unsigned* seqW, const _Float16* xsp,
    float* outp, const int d, const int lane)
{
    const int lr   = lane & 31;    // A row (weights) / B,D column (batch)
    const int half = lane >> 5;    // k-half for A/B; D-row half bit

    // ---- A fragment: row lr = 8q+4h+g -> unit u_r = 2q+1-h, gate g ----
    const int q_r = lr >> 3;
    const int h_r = (lr >> 2) & 1;
    const int g   = lr & 3;        // 0=r 1=z 2=i_n 3=h_n
    const int u_r = 2 * q_r + 1 - h_r;
    const bool rv = (q_r < 3) && (u_r < 5);   // rows 16-19 (u=5) & 24-31 zero

    f16x8 af;
#pragma unroll
    for (int e = 0; e < 8; e++) {
        const int k = 8 * half + e;           // elem e <-> k = 8*half + e
        float v = 0.f;
        if (rv) {
            if (!IS_L0) {
                if (k < 10) {                       // input channels
                    const int j = (k & 1) * 5 + (k >> 1);   // prev-layer concat col
                    if (g == 0)      v = SIG_SCALE  * wih[u_r * 10 + j];
                    else if (g == 1) v = SIG_SCALE  * wih[(5 + u_r) * 10 + j];
                    else if (g == 2) v = TANH_SCALE * wih[(10 + u_r) * 10 + j];
                } else if (k < 15) {                // own-dir hidden
                    const int uh = k - 10;
                    if (g == 0)      v = SIG_SCALE  * whh[u_r * 5 + uh];
                    else if (g == 1) v = SIG_SCALE  * whh[(5 + u_r) * 5 + uh];
                    else if (g == 3) v = TANH_SCALE * whh[(10 + u_r) * 5 + uh];
                }
            } else {
                if (k == 0) {                       // input dim 1
                    if (g == 0)      v = SIG_SCALE  * wih[u_r];
                    else if (g == 1) v = SIG_SCALE  * wih[5 + u_r];
                    else if (g == 2) v = TANH_SCALE * wih[10 + u_r];
                } else if (k >= 10 && k < 15) {
                    const int uh = k - 10;
                    if (g == 0)      v = SIG_SCALE  * whh[u_r * 5 + uh];
                    else if (g == 1) v = SIG_SCALE  * whh[(5 + u_r) * 5 + uh];
                    else if (g == 3) v = TANH_SCALE * whh[(10 + u_r) * 5 + uh];
                }
            }
        }
        af[e] = (_Float16)v;
    }

    // ---- bias fragment (C): quad q -> unit u = 2q+1-half ----
    f32x16 bc;
#pragma unroll
    for (int q = 0; q < 4; q++) {
        const int u = 2 * q + 1 - half;
        float b0 = 0.f, b1 = 0.f, b2 = 0.f, b3 = 0.f;
        if (q < 3 && u < 5) {
            b0 = SIG_SCALE  * (bih[u] + bhh[u]);
            b1 = SIG_SCALE  * (bih[5 + u] + bhh[5 + u]);
            b2 = TANH_SCALE * bih[10 + u];
            b3 = TANH_SCALE * bhh[10 + u];
        }
        bc[4 * q + 0] = b0; bc[4 * q + 1] = b1;
        bc[4 * q + 2] = b2; bc[4 * q + 3] = b3;
    }

    // ---- step loop ----
    const int sdir = d ? -1 : 1;
    const int p0   = d ? (T - 1) : 0;
    const unsigned* rbase = seqR + p0 * 160 + lr;            // planes at +0/+32/+64/+96/+128
    const int r0off = half ? 128 : 0;                        // half1 reads plane4 (ch8,9)
    const _Float16* xp = xsp + p0 * 32 + lr;
    _Float16* wbase = (_Float16*)seqW + p0 * 320 + lr * 2 + d;  // [pos][u][col][d]
    const int rstep = sdir * 160, wstep = sdir * 320, xstep = sdir * 32;
    const int paddr = (lane ^ 32) << 2;                      // cross-half partner

    // h0 = unit (1-half), h1 = unit (3-half), h2 = unit 4 (half1; dead on half0)
    float h0 = 0.f, h1 = 0.f, h2 = 0.f;
    unsigned pb1 = 0, pb2 = 0, pb3 = 0;                      // h-slots of B (k10..15)

    // prefetch step 0's x-channels (recurrence-independent)
    unsigned c0 = 0, c1 = 0, c2 = 0, c3 = 0, xv = 0;
    if constexpr (!IS_L0) {
        c0 = rbase[r0off]; c1 = rbase[32]; c2 = rbase[64]; c3 = rbase[96];
    } else {
        xv = (unsigned)*(const unsigned short*)xp;
    }

#pragma unroll 2
    for (int s = 0; s < NT; s++) {
        // B operand: half0 = x channels 0..7; half1 = [x8,x9][h0,h1][h2,h3][h4,0]
        union { f16x8 v; unsigned u[4]; } B;
        if constexpr (!IS_L0) {
            B.u[0] = c0;
            B.u[1] = half ? pb1 : c1;
            B.u[2] = half ? pb2 : c2;
            B.u[3] = half ? pb3 : c3;
        } else {
            B.u[0] = half ? 0u : xv;
            B.u[1] = half ? pb1 : 0u;
            B.u[2] = half ? pb2 : 0u;
            B.u[3] = half ? pb3 : 0u;
        }

        // issue next step's prefetch now -> latency hides under MFMA+activations
        if (s + 1 < NT) {
            if constexpr (!IS_L0) {
                rbase += rstep;
                c0 = rbase[r0off]; c1 = rbase[32]; c2 = rbase[64]; c3 = rbase[96];
            } else {
                xp += xstep;
                xv = (unsigned)*(const unsigned short*)xp;
            }
        }

        const f32x16 D = __builtin_amdgcn_mfma_f32_32x32x16_f16(af, B.v, bc, 0, 0, 0);

        // activations: quad q holds (r, z, i_n, h_n) of unit 2q+1-half
        float r, z, n;
        r = sig_s(D[0]); z = sig_s(D[1]);
        n = tanh_s(fmaf(r, D[3], D[2]));
        h0 = fmaf(z, h0 - n, n);
        r = sig_s(D[4]); z = sig_s(D[5]);
        n = tanh_s(fmaf(r, D[7], D[6]));
        h1 = fmaf(z, h1 - n, n);

        // issue the single cross-half exchange early: half0 sends [h_u1, h_u3];
        // its LDS round-trip hides under the independent unit-4 chain below.
        const _Float16 q0f = (_Float16)h0, q1f = (_Float16)h1;
        const unsigned pks = packh(q0f, q1f);
        const unsigned o = (unsigned)__builtin_amdgcn_ds_bpermute(paddr, (int)pks);

        // unit 4 (quad 2): rows zero on half0 -> harmless h2=0 there; no branch
        r = sig_s(D[8]); z = sig_s(D[9]);
        n = tanh_s(fmaf(r, D[11], D[10]));
        h2 = fmaf(z, h2 - n, n);
        const _Float16 q2f = (_Float16)h2;

        // half1 merges own {u0,u2,u4} with partner {u1,u3}:
        pb1 = __builtin_amdgcn_perm(pks, o, 0x01000504u);    // [own.lo16, o.lo16] = [h_u0, h_u1]
        pb2 = __builtin_amdgcn_perm(pks, o, 0x03020706u);    // [own.hi16, o.hi16] = [h_u2, h_u3]
        pb3 = packh(q2f, (_Float16)0.f);                     // [h_u4, 0]

        if constexpr (WRITE) {
            wbase[(1 - half) * 64] = q0f;                    // plane u = 1-half
            wbase[(3 - half) * 64] = q1f;                    // plane u = 3-half
            if (half) wbase[4 * 64] = q2f;                   // plane u = 4
            wbase += wstep;
        }
    }

    if constexpr (STORE) {               // ys[T-1] for this direction
        outp[1 - half] = h0;
        outp[3 - half] = h1;
        if (half) outp[4] = h2;
    }
}

__global__ void __launch_bounds__(128, 2) gru_all(
    const float* __restrict__ x,
    const float* __restrict__ wih0, const float* __restrict__ whh0,
    const float* __restrict__ bih0, const float* __restrict__ bhh0,
    const float* __restrict__ wihL, const float* __restrict__ whhL,
    const float* __restrict__ bihL, const float* __restrict__ bhhL,
    float* __restrict__ out)
{
    __shared__ unsigned seqA[T][5][32];      // 19200 B
    __shared__ unsigned seqB[T][5][32];      // 19200 B
    __shared__ _Float16 xs[T][32];           // 1920 B

    const int tid  = threadIdx.x;
    const int d    = tid >> 6;               // wave0 = fwd, wave1 = bwd
    const int lane = tid & 63;
    const int lr   = lane & 31;
    const long base = (long)blockIdx.x * 32;

    // stage x (coalesced, f32 -> f16)
    for (int f = tid; f < 32 * T; f += 128) {
        const int bb = f / T, tt = f - bb * T;
        xs[tt][bb] = (_Float16)x[(base + bb) * T + tt];
    }
    __syncthreads();

    run_layer<true, T, true, false>(wih0 + d * 15, whh0 + d * 75,
                                    bih0 + d * 15, bhh0 + d * 15,
                                    &seqB[0][0][0], &seqA[0][0][0], &xs[0][0],
                                    nullptr, d, lane);
    __syncthreads();

    {   // layer 1: seqA -> seqB
        const int od = d;
        run_layer<false, T, true, false>(wihL + od * 150, whhL + od * 75,
                                         bihL + od * 15, bhhL + od * 15,
                                         &seqA[0][0][0], &seqB[0][0][0], &xs[0][0],
                                         nullptr, d, lane);
    }
    __syncthreads();
    {   // layer 2: seqB -> seqA
        const int od = 2 + d;
        run_layer<false, T, true, false>(wihL + od * 150, whhL + od * 75,
                                         bihL + od * 15, bhhL + od * 15,
                                         &seqB[0][0][0], &seqA[0][0][0], &xs[0][0],
                                         nullptr, d, lane);
    }
    __syncthreads();
    {   // layer 3: seqA -> seqB
        const int od = 4 + d;
        run_layer<false, T, true, false>(wihL + od * 150, whhL + od * 75,
                                         bihL + od * 15, bhhL + od * 15,
                                         &seqA[0][0][0], &seqB[0][0][0], &xs[0][0],
                                         nullptr, d, lane);
    }
    __syncthreads();
    {   // layer 4: no seq write; fwd stores after 30 steps, bwd after 1 step
        const int od = 6 + d;
        float* op = out + (base + lr) * 10 + d * 5;
        if (d == 0)
            run_layer<false, T, false, true>(wihL + od * 150, whhL + od * 75,
                                             bihL + od * 15, bhhL + od * 15,
                                             &seqB[0][0][0], &seqA[0][0][0], &xs[0][0],
                                             op, d, lane);
        else
            run_layer<false, 1, false, true>(wihL + od * 150, whhL + od * 75,
                                             bihL + od * 15, bhhL + od * 15,
                                             &seqB[0][0][0], &seqA[0][0][0], &xs[0][0],
                                             op, d, lane);
    }
}

extern "C" void kernel_launch(void* const* d_in, const int* in_sizes, int n_in,
                              void* d_out, int out_size, void* d_ws, size_t ws_size,
                              hipStream_t stream) {
    const float* x    = (const float*)d_in[0];
    const float* wih0 = (const float*)d_in[1];
    const float* whh0 = (const float*)d_in[2];
    const float* bih0 = (const float*)d_in[3];
    const float* bhh0 = (const float*)d_in[4];
    const float* wihL = (const float*)d_in[5];
    const float* whhL = (const float*)d_in[6];
    const float* bihL = (const float*)d_in[7];
    const float* bhhL = (const float*)d_in[8];
    float* out = (float*)d_out;

    const int blocks = NB / 32;   // 32 batch elements per 128-thread block
    gru_all<<<blocks, 128, 0, stream>>>(x, wih0, whh0, bih0, bhh0,
                                        wihL, whhL, bihL, bhhL, out);
}